// Round 3
// baseline (257.439 us; speedup 1.0000x reference)
//
#include <hip/hip_runtime.h>
#include <hip/hip_bf16.h>
#include <stdint.h>

// Problem constants
#define M_TOK 2048   // B*S
#define N_OUT 4096   // OUT_F
#define K_IN  4096   // IN_F
#define GROUPSZ 128
#define NGRP  32

typedef __bf16 bf16_t;
typedef bf16_t bf16x4 __attribute__((ext_vector_type(4)));
typedef bf16_t bf16x8 __attribute__((ext_vector_type(8)));
typedef float  floatx4 __attribute__((ext_vector_type(4)));

__device__ __forceinline__ bf16_t f2bf(float f) { return (bf16_t)f; }

// ---------------- Kernel 1: x fp32 -> bf16 (8 elems/thread, 2x float4 loads)
__global__ __launch_bounds__(256) void convert_x_kernel(
    const float* __restrict__ x, bf16_t* __restrict__ xb) {
  size_t i = ((size_t)blockIdx.x * blockDim.x + threadIdx.x) * 8;
  float4 a = *(const float4*)(x + i);
  float4 b = *(const float4*)(x + i + 4);
  bf16x8 o;
  o[0] = f2bf(a.x); o[1] = f2bf(a.y); o[2] = f2bf(a.z); o[3] = f2bf(a.w);
  o[4] = f2bf(b.x); o[5] = f2bf(b.y); o[6] = f2bf(b.z); o[7] = f2bf(b.w);
  *(bf16x8*)(xb + i) = o;
}

// ---------------- Kernel 2: w int32 * s_w -> bf16 (8 elems/thread, 2x int4)
// w_q flat layout: [o][g][k'] = o*4096 + g*128 + k'  -> row-major (O, K) = B^T
// s_w flat layout: [g][o] = g*4096 + o
__global__ __launch_bounds__(256) void convert_w_kernel(
    const int* __restrict__ wq, const float* __restrict__ sw,
    bf16_t* __restrict__ wb) {
  size_t t = (size_t)blockIdx.x * blockDim.x + threadIdx.x; // 2M threads
  int o  = (int)(t >> 9);             // 512 chunks of 8 per K-row
  int kc = ((int)t & 511) << 3;       // k base, 8 consecutive k (same group: 8|128)
  float s = sw[(kc >> 7) * N_OUT + o];
  const int* src = wq + (size_t)o * K_IN + kc;
  int4 a = *(const int4*)(src);
  int4 b = *(const int4*)(src + 4);
  bf16x8 ov;
  ov[0] = f2bf((float)a.x * s); ov[1] = f2bf((float)a.y * s);
  ov[2] = f2bf((float)a.z * s); ov[3] = f2bf((float)a.w * s);
  ov[4] = f2bf((float)b.x * s); ov[5] = f2bf((float)b.y * s);
  ov[6] = f2bf((float)b.z * s); ov[7] = f2bf((float)b.w * s);
  *(bf16x8*)(wb + (size_t)o * K_IN + kc) = ov;
}

// ---------------- Kernel 3: split-K GEMM C += A(2048xK) * Bt(4096xK)^T (+bias)
// m97 structure: 128x128 tile, BK=64, 4 waves (2x2), 4x4 frags of 16x16x32 bf16,
// global_load_lds width=16 staging, XOR-swizzled LDS chunk layout.
// Split-K=2: grid.z selects K-half; 1024 blocks = 4/CU (was 2/CU — occupancy
// was the round-2 limiter). Output via unsafeAtomicAdd onto zero-initialized C;
// 2 addends + fp-add commutativity => bitwise-deterministic result.
#define BM 128
#define BN 128
#define BK 64
#define KSPLIT 2
#define KHALF (K_IN / KSPLIT)

__global__ __launch_bounds__(256) void gemm_bias_kernel(
    const bf16_t* __restrict__ A, const bf16_t* __restrict__ Bt,
    const float* __restrict__ bias, float* __restrict__ C) {
  __shared__ bf16_t As[BM * BK];   // 16 KB
  __shared__ bf16_t Bs[BN * BK];   // 16 KB

  const int tid  = threadIdx.x;
  const int lane = tid & 63;
  const int wave = tid >> 6;
  const int bm = blockIdx.y;
  const int bn = blockIdx.x;
  const int kz = blockIdx.z;
  const int wm = wave >> 1;        // 0..1
  const int wn = wave & 1;         // 0..1

  const int rowA0 = bm * BM;
  const int rowB0 = bn * BN;

  floatx4 acc[4][4];
#pragma unroll
  for (int i = 0; i < 4; ++i)
#pragma unroll
    for (int j = 0; j < 4; ++j) acc[i][j] = (floatx4)0.0f;

  const int quad = lane >> 4;      // 0..3
  const int l16  = lane & 15;

  const int kbeg = kz * KHALF;
  for (int k0 = kbeg; k0 < kbeg + KHALF; k0 += BK) {
    __syncthreads();   // previous compute done before LDS overwrite
    // Stage A-tile and B-tile: 1024 chunks of 16 B each, 4 per thread.
    // LDS dest is wave-uniform base + lane*16 (global_load_lds constraint).
    // Global source column is XOR-swizzled so LDS reads are conflict-free.
#pragma unroll
    for (int i = 0; i < 4; ++i) {
      int chunk = i * 256 + tid;            // tid = wave*64 + lane, wave-contiguous
      int row = chunk >> 3;                 // tile row 0..127
      int csw = (chunk & 7) ^ (row & 7);    // swizzled k-chunk 0..7
      int col = csw << 3;                   // k elem offset 0..56
      const bf16_t* srcA = A  + (size_t)(rowA0 + row) * K_IN + k0 + col;
      const bf16_t* srcB = Bt + (size_t)(rowB0 + row) * K_IN + k0 + col;
      __builtin_amdgcn_global_load_lds(
          (const __attribute__((address_space(1))) void*)srcA,
          (__attribute__((address_space(3))) void*)(As + (size_t)(i * 256 + wave * 64) * 8),
          16, 0, 0);
      __builtin_amdgcn_global_load_lds(
          (const __attribute__((address_space(1))) void*)srcB,
          (__attribute__((address_space(3))) void*)(Bs + (size_t)(i * 256 + wave * 64) * 8),
          16, 0, 0);
    }
    __syncthreads();   // compiler emits vmcnt(0) drain before barrier

#pragma unroll
    for (int kk = 0; kk < BK; kk += 32) {
      bf16x8 af[4], bfr[4];
      const int kc8 = (kk >> 3) + quad;     // k-chunk index 0..7
#pragma unroll
      for (int i = 0; i < 4; ++i) {
        int r = wm * 64 + i * 16 + l16;     // m index
        af[i] = *(const bf16x8*)(As + (size_t)(r * 8 + (kc8 ^ (r & 7))) * 8);
      }
#pragma unroll
      for (int j = 0; j < 4; ++j) {
        int r = wn * 64 + j * 16 + l16;     // n index
        bfr[j] = *(const bf16x8*)(Bs + (size_t)(r * 8 + (kc8 ^ (r & 7))) * 8);
      }
#pragma unroll
      for (int i = 0; i < 4; ++i)
#pragma unroll
        for (int j = 0; j < 4; ++j)
          acc[i][j] = __builtin_amdgcn_mfma_f32_16x16x32_bf16(af[i], bfr[j], acc[i][j], 0, 0, 0);
    }
  }

  // Epilogue: C/D layout col = lane&15 (n), row = quad*4 + reg (m).
  // kz==0 half contributes the bias; C was zero-initialized via memset node.
#pragma unroll
  for (int j = 0; j < 4; ++j) {
    int col = rowB0 + wn * 64 + j * 16 + l16;
    float bv = (kz == 0) ? bias[col] : 0.0f;
#pragma unroll
    for (int i = 0; i < 4; ++i) {
      int rowbase = rowA0 + wm * 64 + i * 16 + quad * 4;
#pragma unroll
      for (int r = 0; r < 4; ++r) {
        unsafeAtomicAdd(&C[(size_t)(rowbase + r) * N_OUT + col], acc[i][j][r] + bv);
      }
    }
  }
}

extern "C" void kernel_launch(void* const* d_in, const int* in_sizes, int n_in,
                              void* d_out, int out_size, void* d_ws, size_t ws_size,
                              hipStream_t stream) {
  const float* x    = (const float*)d_in[0];
  const int*   wq   = (const int*)d_in[1];     // integer input -> int32 per harness
  const float* sw   = (const float*)d_in[2];
  const float* bias = (const float*)d_in[3];
  float* out = (float*)d_out;

  bf16_t* xb = (bf16_t*)d_ws;                                     // 16 MB
  bf16_t* wb = (bf16_t*)((char*)d_ws + (size_t)M_TOK * K_IN * 2); // 32 MB

  // Zero-init C for the split-K atomic accumulation (legal graph node).
  hipMemsetAsync(out, 0, (size_t)M_TOK * N_OUT * sizeof(float), stream);

  {
    int nthreads = M_TOK * K_IN / 8;            // 1M threads
    convert_x_kernel<<<nthreads / 256, 256, 0, stream>>>(x, xb);
  }
  {
    int nthreads = N_OUT * K_IN / 8;            // 2M threads
    convert_w_kernel<<<nthreads / 256, 256, 0, stream>>>(wq, sw, wb);
  }
  {
    dim3 grid(N_OUT / BN, M_TOK / BM, KSPLIT);  // (32, 16, 2) = 1024 blocks
    gemm_bias_kernel<<<grid, 256, 0, stream>>>(xb, wb, bias, out);
  }
}

// Round 4
// 200.294 us; speedup vs baseline: 1.2853x; 1.2853x over previous
//
#include <hip/hip_runtime.h>
#include <hip/hip_bf16.h>
#include <stdint.h>

// Problem constants
#define M_TOK 2048   // B*S
#define N_OUT 4096   // OUT_F
#define K_IN  4096   // IN_F
#define GROUPSZ 128
#define NGRP  32

typedef __bf16 bf16_t;
typedef bf16_t bf16x4 __attribute__((ext_vector_type(4)));
typedef bf16_t bf16x8 __attribute__((ext_vector_type(8)));
typedef float  floatx4 __attribute__((ext_vector_type(4)));

__device__ __forceinline__ bf16_t f2bf(float f) { return (bf16_t)f; }

// ---------------- Kernel 1: fused conversion pass (one dispatch).
// Blocks [0, XCONV_BLOCKS): x fp32 -> bf16, 8 elems/thread (2x float4).
// Blocks [XCONV_BLOCKS, ...): w int32 * s_w -> bf16, 8 elems/thread (2x int4).
// w_q flat layout: [o][g][k'] = o*4096 + g*128 + k'  -> row-major (O, K) = B^T
// s_w flat layout: [g][o] = g*4096 + o
#define XCONV_BLOCKS (M_TOK * K_IN / 8 / 256)   // 4096
#define WCONV_BLOCKS (N_OUT * K_IN / 8 / 256)   // 8192

__global__ __launch_bounds__(256) void convert_kernel(
    const float* __restrict__ x, const int* __restrict__ wq,
    const float* __restrict__ sw, bf16_t* __restrict__ xb,
    bf16_t* __restrict__ wb) {
  int b = blockIdx.x;
  if (b < XCONV_BLOCKS) {
    size_t i = ((size_t)b * 256 + threadIdx.x) * 8;
    float4 a0 = *(const float4*)(x + i);
    float4 a1 = *(const float4*)(x + i + 4);
    bf16x8 o;
    o[0] = f2bf(a0.x); o[1] = f2bf(a0.y); o[2] = f2bf(a0.z); o[3] = f2bf(a0.w);
    o[4] = f2bf(a1.x); o[5] = f2bf(a1.y); o[6] = f2bf(a1.z); o[7] = f2bf(a1.w);
    *(bf16x8*)(xb + i) = o;
  } else {
    size_t t = (size_t)(b - XCONV_BLOCKS) * 256 + threadIdx.x; // 2M threads
    int o  = (int)(t >> 9);             // 512 chunks of 8 per K-row
    int kc = ((int)t & 511) << 3;       // 8 consecutive k (same group: 8|128)
    float s = sw[(kc >> 7) * N_OUT + o];
    const int* src = wq + (size_t)o * K_IN + kc;
    int4 a = *(const int4*)(src);
    int4 c = *(const int4*)(src + 4);
    bf16x8 ov;
    ov[0] = f2bf((float)a.x * s); ov[1] = f2bf((float)a.y * s);
    ov[2] = f2bf((float)a.z * s); ov[3] = f2bf((float)a.w * s);
    ov[4] = f2bf((float)c.x * s); ov[5] = f2bf((float)c.y * s);
    ov[6] = f2bf((float)c.z * s); ov[7] = f2bf((float)c.w * s);
    *(bf16x8*)(wb + (size_t)o * K_IN + kc) = ov;
  }
}

// ---------------- Kernel 2: GEMM C = A(2048xK) * Bt(4096xK)^T + bias
// 128x128 tile, BK=64, *8 waves* (4x2 layout, 512 threads), wave-tile 32x64,
// 2x4 frags of 16x16x32 bf16, global_load_lds width=16 staging, XOR-swizzled
// LDS chunk layout (conflict-free reads, verified round 2).
// 8 waves/block: grid of 512 caps residency at 2 blocks/CU, so waves/SIMD
// was the round-2/3 limiter (2/SIMD). 512-thread blocks give 4 waves/SIMD at
// the same grid, same global traffic, same staging:MFMA ratio.
#define BM 128
#define BN 128
#define BK 64

__global__ __launch_bounds__(512) void gemm_bias_kernel(
    const bf16_t* __restrict__ A, const bf16_t* __restrict__ Bt,
    const float* __restrict__ bias, float* __restrict__ C) {
  __shared__ bf16_t As[BM * BK];   // 16 KB
  __shared__ bf16_t Bs[BN * BK];   // 16 KB

  const int tid  = threadIdx.x;
  const int lane = tid & 63;
  const int wave = tid >> 6;       // 0..7
  const int bm = blockIdx.y;
  const int bn = blockIdx.x;
  const int wm = wave >> 1;        // 0..3 -> 32-row slab
  const int wn = wave & 1;         // 0..1 -> 64-col slab

  const int rowA0 = bm * BM;
  const int rowB0 = bn * BN;

  floatx4 acc[2][4];
#pragma unroll
  for (int i = 0; i < 2; ++i)
#pragma unroll
    for (int j = 0; j < 4; ++j) acc[i][j] = (floatx4)0.0f;

  const int quad = lane >> 4;      // 0..3
  const int l16  = lane & 15;

  for (int k0 = 0; k0 < K_IN; k0 += BK) {
    __syncthreads();   // previous compute done before LDS overwrite
    // Stage A-tile and B-tile: 1024 chunks of 16 B each per matrix,
    // 2 per thread per matrix. LDS dest is wave-uniform base + lane*16
    // (global_load_lds constraint). Global source column is XOR-swizzled
    // so LDS fragment reads are conflict-free.
#pragma unroll
    for (int i = 0; i < 2; ++i) {
      int chunk = i * 512 + tid;            // wave-contiguous
      int row = chunk >> 3;                 // tile row 0..127
      int csw = (chunk & 7) ^ (row & 7);    // swizzled k-chunk 0..7
      int col = csw << 3;                   // k elem offset 0..56
      const bf16_t* srcA = A  + (size_t)(rowA0 + row) * K_IN + k0 + col;
      const bf16_t* srcB = Bt + (size_t)(rowB0 + row) * K_IN + k0 + col;
      __builtin_amdgcn_global_load_lds(
          (const __attribute__((address_space(1))) void*)srcA,
          (__attribute__((address_space(3))) void*)(As + (size_t)(i * 512 + wave * 64) * 8),
          16, 0, 0);
      __builtin_amdgcn_global_load_lds(
          (const __attribute__((address_space(1))) void*)srcB,
          (__attribute__((address_space(3))) void*)(Bs + (size_t)(i * 512 + wave * 64) * 8),
          16, 0, 0);
    }
    __syncthreads();   // compiler emits vmcnt(0) drain before barrier

#pragma unroll
    for (int kk = 0; kk < BK; kk += 32) {
      bf16x8 af[2], bfr[4];
      const int kc8 = (kk >> 3) + quad;     // k-chunk index 0..7
#pragma unroll
      for (int i = 0; i < 2; ++i) {
        int r = wm * 32 + i * 16 + l16;     // m index
        af[i] = *(const bf16x8*)(As + (size_t)(r * 8 + (kc8 ^ (r & 7))) * 8);
      }
#pragma unroll
      for (int j = 0; j < 4; ++j) {
        int r = wn * 64 + j * 16 + l16;     // n index
        bfr[j] = *(const bf16x8*)(Bs + (size_t)(r * 8 + (kc8 ^ (r & 7))) * 8);
      }
#pragma unroll
      for (int i = 0; i < 2; ++i)
#pragma unroll
        for (int j = 0; j < 4; ++j)
          acc[i][j] = __builtin_amdgcn_mfma_f32_16x16x32_bf16(af[i], bfr[j], acc[i][j], 0, 0, 0);
    }
  }

  // Epilogue: C/D layout col = lane&15 (n), row = quad*4 + reg (m). Fused bias.
#pragma unroll
  for (int j = 0; j < 4; ++j) {
    int col = rowB0 + wn * 64 + j * 16 + l16;
    float bv = bias[col];
#pragma unroll
    for (int i = 0; i < 2; ++i) {
      int rowbase = rowA0 + wm * 32 + i * 16 + quad * 4;
#pragma unroll
      for (int r = 0; r < 4; ++r) {
        C[(size_t)(rowbase + r) * N_OUT + col] = acc[i][j][r] + bv;
      }
    }
  }
}

extern "C" void kernel_launch(void* const* d_in, const int* in_sizes, int n_in,
                              void* d_out, int out_size, void* d_ws, size_t ws_size,
                              hipStream_t stream) {
  const float* x    = (const float*)d_in[0];
  const int*   wq   = (const int*)d_in[1];     // integer input -> int32 per harness
  const float* sw   = (const float*)d_in[2];
  const float* bias = (const float*)d_in[3];
  float* out = (float*)d_out;

  bf16_t* xb = (bf16_t*)d_ws;                                     // 16 MB
  bf16_t* wb = (bf16_t*)((char*)d_ws + (size_t)M_TOK * K_IN * 2); // 32 MB

  {
    int nblocks = XCONV_BLOCKS + WCONV_BLOCKS;  // 12288
    convert_kernel<<<nblocks, 256, 0, stream>>>(x, wq, sw, xb, wb);
  }
  {
    dim3 grid(N_OUT / BN, M_TOK / BM);          // (32, 16) = 512 blocks
    gemm_bias_kernel<<<grid, 512, 0, stream>>>(xb, wb, bias, out);
  }
}

// Round 5
// 199.128 us; speedup vs baseline: 1.2928x; 1.0059x over previous
//
#include <hip/hip_runtime.h>
#include <hip/hip_bf16.h>
#include <stdint.h>

// Problem constants
#define M_TOK 2048   // B*S
#define N_OUT 4096   // OUT_F
#define K_IN  4096   // IN_F
#define GROUPSZ 128
#define NGRP  32

typedef __bf16 bf16_t;
typedef bf16_t bf16x4 __attribute__((ext_vector_type(4)));
typedef bf16_t bf16x8 __attribute__((ext_vector_type(8)));
typedef float  floatx4 __attribute__((ext_vector_type(4)));

__device__ __forceinline__ bf16_t f2bf(float f) { return (bf16_t)f; }

// ---------------- Kernel 1: fused conversion pass (one dispatch).
// Blocks [0, XCONV_BLOCKS): x fp32 -> bf16, 8 elems/thread (2x float4).
// Blocks [XCONV_BLOCKS, ...): w int32 * s_w -> bf16, 8 elems/thread (2x int4).
// w_q flat layout: [o][g][k'] = o*4096 + g*128 + k'  -> row-major (O, K) = B^T
// s_w flat layout: [g][o] = g*4096 + o
#define XCONV_BLOCKS (M_TOK * K_IN / 8 / 256)   // 4096
#define WCONV_BLOCKS (N_OUT * K_IN / 8 / 256)   // 8192

__global__ __launch_bounds__(256) void convert_kernel(
    const float* __restrict__ x, const int* __restrict__ wq,
    const float* __restrict__ sw, bf16_t* __restrict__ xb,
    bf16_t* __restrict__ wb) {
  int b = blockIdx.x;
  if (b < XCONV_BLOCKS) {
    size_t i = ((size_t)b * 256 + threadIdx.x) * 8;
    float4 a0 = *(const float4*)(x + i);
    float4 a1 = *(const float4*)(x + i + 4);
    bf16x8 o;
    o[0] = f2bf(a0.x); o[1] = f2bf(a0.y); o[2] = f2bf(a0.z); o[3] = f2bf(a0.w);
    o[4] = f2bf(a1.x); o[5] = f2bf(a1.y); o[6] = f2bf(a1.z); o[7] = f2bf(a1.w);
    *(bf16x8*)(xb + i) = o;
  } else {
    size_t t = (size_t)(b - XCONV_BLOCKS) * 256 + threadIdx.x; // 2M threads
    int o  = (int)(t >> 9);             // 512 chunks of 8 per K-row
    int kc = ((int)t & 511) << 3;       // 8 consecutive k (same group: 8|128)
    float s = sw[(kc >> 7) * N_OUT + o];
    const int* src = wq + (size_t)o * K_IN + kc;
    int4 a = *(const int4*)(src);
    int4 c = *(const int4*)(src + 4);
    bf16x8 ov;
    ov[0] = f2bf((float)a.x * s); ov[1] = f2bf((float)a.y * s);
    ov[2] = f2bf((float)a.z * s); ov[3] = f2bf((float)a.w * s);
    ov[4] = f2bf((float)c.x * s); ov[5] = f2bf((float)c.y * s);
    ov[6] = f2bf((float)c.z * s); ov[7] = f2bf((float)c.w * s);
    *(bf16x8*)(wb + (size_t)o * K_IN + kc) = ov;
  }
}

// ---------------- Kernel 2: GEMM C = A(2048xK) * Bt(4096xK)^T + bias
// 128x128 tile, *BK=128* (32 K-iters — halves barrier-drain count vs BK=64),
// 8 waves (4x2, 512 threads), wave-tile 32x64, 2x4 frags of 16x16x32 bf16,
// global_load_lds width=16 staging, XOR-swizzled LDS chunk layout
// (conflict-free reads, verified round 2). LDS 64 KB -> still 2 blocks/CU
// (grid-capped anyway), so this isolates barrier amortization (m132's BK=128
// regression was an occupancy cliff we don't have).
#define BM 128
#define BN 128
#define BK 128

__global__ __launch_bounds__(512) void gemm_bias_kernel(
    const bf16_t* __restrict__ A, const bf16_t* __restrict__ Bt,
    const float* __restrict__ bias, float* __restrict__ C) {
  __shared__ bf16_t As[BM * BK];   // 32 KB
  __shared__ bf16_t Bs[BN * BK];   // 32 KB

  const int tid  = threadIdx.x;
  const int lane = tid & 63;
  const int wave = tid >> 6;       // 0..7
  const int bm = blockIdx.y;
  const int bn = blockIdx.x;
  const int wm = wave >> 1;        // 0..3 -> 32-row slab
  const int wn = wave & 1;         // 0..1 -> 64-col slab

  const int rowA0 = bm * BM;
  const int rowB0 = bn * BN;

  floatx4 acc[2][4];
#pragma unroll
  for (int i = 0; i < 2; ++i)
#pragma unroll
    for (int j = 0; j < 4; ++j) acc[i][j] = (floatx4)0.0f;

  const int quad = lane >> 4;      // 0..3
  const int l16  = lane & 15;

  for (int k0 = 0; k0 < K_IN; k0 += BK) {
    __syncthreads();   // previous compute done before LDS overwrite
    // Stage A-tile and B-tile: 2048 chunks of 16 B each per matrix,
    // 4 per thread per matrix. LDS dest is wave-uniform base + lane*16
    // (global_load_lds constraint). Global source column is XOR-swizzled
    // (16 chunks/row now, mask 15) so LDS fragment reads are conflict-free.
#pragma unroll
    for (int i = 0; i < 4; ++i) {
      int chunk = i * 512 + tid;            // wave-contiguous, 0..2047
      int row = chunk >> 4;                 // tile row 0..127
      int csw = (chunk & 15) ^ (row & 15);  // swizzled k-chunk 0..15
      int col = csw << 3;                   // k elem offset 0..120
      const bf16_t* srcA = A  + (size_t)(rowA0 + row) * K_IN + k0 + col;
      const bf16_t* srcB = Bt + (size_t)(rowB0 + row) * K_IN + k0 + col;
      __builtin_amdgcn_global_load_lds(
          (const __attribute__((address_space(1))) void*)srcA,
          (__attribute__((address_space(3))) void*)(As + (size_t)(i * 512 + wave * 64) * 8),
          16, 0, 0);
      __builtin_amdgcn_global_load_lds(
          (const __attribute__((address_space(1))) void*)srcB,
          (__attribute__((address_space(3))) void*)(Bs + (size_t)(i * 512 + wave * 64) * 8),
          16, 0, 0);
    }
    __syncthreads();   // compiler emits vmcnt(0) drain before barrier

#pragma unroll
    for (int kk = 0; kk < BK; kk += 32) {
      bf16x8 af[2], bfr[4];
      const int kc16 = (kk >> 3) + quad;    // k-chunk index 0..15
#pragma unroll
      for (int i = 0; i < 2; ++i) {
        int r = wm * 32 + i * 16 + l16;     // m index
        af[i] = *(const bf16x8*)(As + (size_t)(r * 16 + (kc16 ^ (r & 15))) * 8);
      }
#pragma unroll
      for (int j = 0; j < 4; ++j) {
        int r = wn * 64 + j * 16 + l16;     // n index
        bfr[j] = *(const bf16x8*)(Bs + (size_t)(r * 16 + (kc16 ^ (r & 15))) * 8);
      }
#pragma unroll
      for (int i = 0; i < 2; ++i)
#pragma unroll
        for (int j = 0; j < 4; ++j)
          acc[i][j] = __builtin_amdgcn_mfma_f32_16x16x32_bf16(af[i], bfr[j], acc[i][j], 0, 0, 0);
    }
  }

  // Epilogue: C/D layout col = lane&15 (n), row = quad*4 + reg (m). Fused bias.
  // Nontemporal stores: C is write-only; avoid write-allocate RFO fetch
  // (round-4 FETCH_SIZE showed ~33 MB of C being read back on partial-line
  // stores).
#pragma unroll
  for (int j = 0; j < 4; ++j) {
    int col = rowB0 + wn * 64 + j * 16 + l16;
    float bv = bias[col];
#pragma unroll
    for (int i = 0; i < 2; ++i) {
      int rowbase = rowA0 + wm * 32 + i * 16 + quad * 4;
#pragma unroll
      for (int r = 0; r < 4; ++r) {
        __builtin_nontemporal_store(acc[i][j][r] + bv,
                                    &C[(size_t)(rowbase + r) * N_OUT + col]);
      }
    }
  }
}

extern "C" void kernel_launch(void* const* d_in, const int* in_sizes, int n_in,
                              void* d_out, int out_size, void* d_ws, size_t ws_size,
                              hipStream_t stream) {
  const float* x    = (const float*)d_in[0];
  const int*   wq   = (const int*)d_in[1];     // integer input -> int32 per harness
  const float* sw   = (const float*)d_in[2];
  const float* bias = (const float*)d_in[3];
  float* out = (float*)d_out;

  bf16_t* xb = (bf16_t*)d_ws;                                     // 16 MB
  bf16_t* wb = (bf16_t*)((char*)d_ws + (size_t)M_TOK * K_IN * 2); // 32 MB

  {
    int nblocks = XCONV_BLOCKS + WCONV_BLOCKS;  // 12288
    convert_kernel<<<nblocks, 256, 0, stream>>>(x, wq, sw, xb, wb);
  }
  {
    dim3 grid(N_OUT / BN, M_TOK / BM);          // (32, 16) = 512 blocks
    gemm_bias_kernel<<<grid, 512, 0, stream>>>(xb, wb, bias, out);
  }
}